// Round 10
// baseline (128.871 us; speedup 1.0000x reference)
//
#include <hip/hip_runtime.h>
#include <math.h>

#define LBF 64  // fused blocks per batch
#define LB 32   // blocks per batch for hist/sum kernels

// ---------------------------------------------------------------------------
// ws layout (memset region first):
//   double pconf[B], ploc[B], phard[B] ; int n_pos[B] ; u32 counter (+pad)
//   u64    prior_fo[B*64]  : packed (iou_bits<<32)|(0xFFFFFFFF-p), atomicMax
//   u32    hist0[B][4096], hist1[B][4096]
//   ---- end memset ----
//   float  conf_neg[B*P]   : also used as pk temp between cohorts
//   u8     best_u8[B*P]    : bit7 = (best iou >= 0.5), bits0-5 = best obj
// ---------------------------------------------------------------------------

__device__ __forceinline__ unsigned long long umax64(unsigned long long a,
                                                     unsigned long long b) {
  return a > b ? a : b;
}
__device__ __forceinline__ float rfl(float x) {
  return __uint_as_float(__builtin_amdgcn_readfirstlane(__float_as_uint(x)));
}

// Fused match+loss. Cohorts of 8 SGPR-resident boxes outer, prior chunks
// inner. pk (per-prior best obj, 6 LSBs stolen) rides in conf_neg between
// cohorts; final cohort emits label/CE/L1/conf_neg/hist0/best_u8. Exact
// per-object (iou,~p) argmax via reg tracking + one LDS epilogue per cohort.
template <int CC>
__global__ __launch_bounds__(256) void mbl_fused(
    const float* __restrict__ locs, const float* __restrict__ scores,
    const float* __restrict__ boxes, const int* __restrict__ labels,
    const float* __restrict__ priors, unsigned long long* __restrict__ prior_fo,
    unsigned char* __restrict__ best_u8, float* __restrict__ conf_neg,
    unsigned* __restrict__ hist0, int* __restrict__ n_pos,
    double* __restrict__ pconf, double* __restrict__ ploc, int P, int n_obj,
    int chunks, int C) {
  const int b = blockIdx.y;
  const int tid = threadIdx.x;
  __shared__ unsigned s_hist[4096];
  __shared__ unsigned s_iou[8][264];
  __shared__ unsigned s_pinv[8][264];
  __shared__ int s_lab[64];
  for (int i = tid; i < 4096; i += 256) s_hist[i] = 0u;
  if (tid < 64) s_lab[tid] = (tid < n_obj) ? labels[(size_t)b * n_obj + tid] : 0;
  __syncthreads();

  const int base = blockIdx.x * chunks * 256;
  const float* bx = boxes + (size_t)b * n_obj * 6;
  const size_t rowb = (size_t)b * P;
  const unsigned msk = ~63u;

  int np_l = 0;
  double cf_l = 0.0, lc_l = 0.0;
  const int COHS = (n_obj + 7) / 8;

  for (int coh = 0; coh < COHS; ++coh) {
    // 8 boxes -> SGPRs (block-uniform)
    float sl0[8], sl1[8], sl2[8], sh0[8], sh1[8], sh2[8], sv[8];
#pragma unroll
    for (int oo = 0; oo < 8; ++oo) {
      const int o = coh * 8 + oo;
      if (o < n_obj) {
        const float* q = bx + (size_t)o * 6;
        sl0[oo] = rfl(q[0]); sl1[oo] = rfl(q[1]); sl2[oo] = rfl(q[2]);
        sh0[oo] = rfl(q[3]); sh1[oo] = rfl(q[4]); sh2[oo] = rfl(q[5]);
        sv[oo] = rfl(((sh0[oo] - sl0[oo]) * (sh1[oo] - sl1[oo])) *
                     (sh2[oo] - sl2[oo]));
      } else {  // dummy object: iou 0 vs everything
        sl0[oo] = sl1[oo] = sl2[oo] = 3e18f;
        sh0[oo] = sh1[oo] = sh2[oo] = 3e18f;
        sv[oo] = 0.f;
      }
    }
    float piou[8];
    unsigned pinv[8];
#pragma unroll
    for (int oo = 0; oo < 8; ++oo) { piou[oo] = 0.f; pinv[oo] = 0u; }

    const bool lastc = (coh == COHS - 1);
    for (int c = 0; c < chunks; ++c) {
      const int p = base + c * 256 + tid;
      const bool act = p < P;
      float lo0, lo1, lo2, hi0, hi1, hi2, vb;
      if (act) {
        const float2 q0 = *(const float2*)(priors + (size_t)p * 6);
        const float2 q1 = *(const float2*)(priors + (size_t)p * 6 + 2);
        const float2 q2 = *(const float2*)(priors + (size_t)p * 6 + 4);
        lo0 = q0.x - q1.y * 0.5f; hi0 = q0.x + q1.y * 0.5f;
        lo1 = q0.y - q2.x * 0.5f; hi1 = q0.y + q2.x * 0.5f;
        lo2 = q1.x - q2.y * 0.5f; hi2 = q1.x + q2.y * 0.5f;
        vb = (q1.y * q2.x) * q2.y;
      } else {  // dummy prior
        lo0 = lo1 = lo2 = hi0 = hi1 = hi2 = 3e18f;
        vb = 0.f;
      }
      unsigned pk = 0u;
      if (coh > 0 && act) pk = __float_as_uint(conf_neg[rowb + p]);
      const unsigned invp = 0xFFFFFFFFu - (unsigned)p;
#pragma unroll
      for (int oo = 0; oo < 8; ++oo) {
        const int o = coh * 8 + oo;
        const float d0 = fminf(sh0[oo], hi0) - fmaxf(sl0[oo], lo0);
        const float d1 = fminf(sh1[oo], hi1) - fmaxf(sl1[oo], lo1);
        const float d2 = fminf(sh2[oo], hi2) - fmaxf(sl2[oo], lo2);
        const float inter = (fmaxf(d0, 0.f) * fmaxf(d1, 0.f)) * fmaxf(d2, 0.f);
        const float un = (sv[oo] + vb) - inter;
        const float iou = inter * __builtin_amdgcn_rcpf(un);
        pk = max(pk, (__float_as_uint(iou) & msk) | (unsigned)(63 - o));
        const bool win = iou > piou[oo];  // strict: first occurrence wins
        piou[oo] = win ? iou : piou[oo];
        pinv[oo] = win ? invp : pinv[oo];
      }
      if (!lastc) {
        if (act) conf_neg[rowb + p] = __uint_as_float(pk);  // pk temp
      } else if (act) {
        const int bo = 63 - (int)(pk & 63u);
        const int posf = pk >= 0x3F000000u;
        const int lab = posf ? s_lab[bo] : 0;
        float conf;
        if (CC == 2) {
          const float2 sc = *(const float2*)(scores + (rowb + p) * 2);
          const float mm = fmaxf(sc.x, sc.y);
          conf = (lab < 0) ? 0.f
                           : (mm + __logf(__expf(sc.x - mm) + __expf(sc.y - mm)) -
                              ((lab == 0) ? sc.x : sc.y));
        } else {
          const float* sp = scores + (rowb + p) * C;
          float m = sp[0];
          for (int cc = 1; cc < C; ++cc) m = fmaxf(m, sp[cc]);
          float se = 0.f;
          for (int cc = 0; cc < C; ++cc) se += __expf(sp[cc] - m);
          conf = (lab < 0) ? 0.f : (m + __logf(se) - sp[lab]);
        }
        float cn = conf;  // lab<0 -> conf==0 -> cn 0 (matches reference)
        if (lab > 0) {
          np_l++;
          cf_l += (double)conf;
          const float* pr = priors + (size_t)p * 6;
          const float* pl = locs + (rowb + p) * 6;
          float ls = 0.f;
          for (int i = 0; i < 3; ++i) {
            const float bl = bx[bo * 6 + i], bh = bx[bo * 6 + i + 3];
            const float c0 = (bl + bh) * 0.5f;
            const float szb = bh - bl;
            const float g = (c0 - pr[i]) / (pr[i + 3] / 10.0f);
            const float g2 = logf(szb / pr[i + 3]) * 5.0f;
            ls += fabsf(pl[i] - g) + fabsf(pl[i + 3] - g2);
          }
          lc_l += (double)ls;
          cn = 0.f;
        }
        conf_neg[rowb + p] = cn;
        atomicAdd(&s_hist[__float_as_uint(cn) >> 20], 1u);
        best_u8[rowb + p] =
            (unsigned char)((unsigned)bo | (posf ? 0x80u : 0u));
      }
    }

    // per-cohort exact (iou,~p) block argmax epilogue
    __syncthreads();  // previous epilogue readers done before overwrite
#pragma unroll
    for (int oo = 0; oo < 8; ++oo) {
      s_iou[oo][tid] = __float_as_uint(piou[oo]);
      s_pinv[oo][tid] = pinv[oo];
    }
    __syncthreads();
    const int obj8 = tid >> 5, j = tid & 31;
    unsigned long long m = 0ULL;
#pragma unroll
    for (int i = 0; i < 8; ++i) {
      const int col = j + 32 * i;
      m = umax64(m, ((unsigned long long)s_iou[obj8][col] << 32) |
                        s_pinv[obj8][col]);
    }
#pragma unroll
    for (int off = 1; off < 32; off <<= 1)
      m = umax64(m, __shfl_xor(m, off, 64));
    if (j == 0) {
      const int o = coh * 8 + obj8;
      if (o < n_obj) atomicMax(&prior_fo[(size_t)b * 64 + o], m);
    }
  }

  __shared__ int r_np[256];
  __shared__ double r_c[256];
  __shared__ double r_l[256];
  r_np[tid] = np_l;
  r_c[tid] = cf_l;
  r_l[tid] = lc_l;
  __syncthreads();
  for (int s = 128; s > 0; s >>= 1) {
    if (tid < s) {
      r_np[tid] += r_np[tid + s];
      r_c[tid] += r_c[tid + s];
      r_l[tid] += r_l[tid + s];
    }
    __syncthreads();
  }
  if (tid == 0 && r_np[0] > 0) {
    atomicAdd(&n_pos[b], r_np[0]);
    atomicAdd(&pconf[b], r_c[0]);
    atomicAdd(&ploc[b], r_l[0]);
  }
  for (int i = tid; i < 4096; i += 256)
    if (s_hist[i]) atomicAdd(&hist0[(size_t)b * 4096 + i], s_hist[i]);
}

// Forced-match fixup: <= n_obj priors per batch, serial in one thread.
__global__ void mbl_fixup(
    const float* __restrict__ locs, const float* __restrict__ scores,
    const float* __restrict__ boxes, const int* __restrict__ labels,
    const float* __restrict__ priors,
    const unsigned long long* __restrict__ prior_fo,
    const unsigned char* __restrict__ best_u8, float* __restrict__ conf_neg,
    unsigned* __restrict__ hist0, int* __restrict__ n_pos,
    double* __restrict__ pconf, double* __restrict__ ploc, int P, int n_obj,
    int C) {
  const int b = blockIdx.x;
  if (threadIdx.x != 0) return;
  const size_t rowb = (size_t)b * P;
  unsigned fp[64];
  for (int o = 0; o < n_obj; ++o)
    fp[o] = 0xFFFFFFFFu - (unsigned)(prior_fo[(size_t)b * 64 + o] & 0xFFFFFFFFull);
  int d_np = 0;
  double d_cf = 0.0, d_lc = 0.0;
  for (int o = 0; o < n_obj; ++o) {
    const unsigned p = fp[o];
    if (p >= (unsigned)P) continue;  // degenerate (no overlap anywhere)
    bool last = true;
    for (int o2 = o + 1; o2 < n_obj; ++o2)
      if (fp[o2] == p) { last = false; break; }
    if (!last) continue;  // numpy .at[].set: last object wins
    const unsigned char bp = best_u8[rowb + p];
    const int obj_o = bp & 0x7F;
    const int posf_o = bp >> 7;
    if (posf_o && obj_o == o) continue;  // already matched to o
    const int lab_old = posf_o ? labels[(size_t)b * n_obj + obj_o] : 0;
    const int lab_new = labels[(size_t)b * n_obj + o];
    // CE pieces
    const float* sp = scores + (rowb + p) * C;
    float m = sp[0];
    for (int cc = 1; cc < C; ++cc) m = fmaxf(m, sp[cc]);
    float se = 0.f;
    for (int cc = 0; cc < C; ++cc) se += __expf(sp[cc] - m);
    const float lse = m + __logf(se);
    // conf_neg update (exact old value read back)
    const float cn_old = conf_neg[rowb + p];
    float cn_new = 0.f;
    if (lab_new == 0) cn_new = lse - sp[0];
    if (__float_as_uint(cn_new) != __float_as_uint(cn_old)) {
      hist0[(size_t)b * 4096 + (__float_as_uint(cn_old) >> 20)] -= 1u;
      hist0[(size_t)b * 4096 + (__float_as_uint(cn_new) >> 20)] += 1u;
      conf_neg[rowb + p] = cn_new;
    }
    d_np += (lab_new > 0) - (lab_old > 0);
    const float* pr = priors + (size_t)p * 6;
    const float* pl = locs + (rowb + p) * 6;
    for (int which = 0; which < 2; ++which) {
      const int lab = which ? lab_new : lab_old;
      const int obj = which ? o : obj_o;
      if (lab <= 0) continue;
      const double sgn = which ? 1.0 : -1.0;
      d_cf += sgn * (double)(lse - sp[lab]);
      const float* q = boxes + ((size_t)b * n_obj + obj) * 6;
      float ls = 0.f;
      for (int i = 0; i < 3; ++i) {
        const float bl = q[i], bh = q[i + 3];
        const float c0 = (bl + bh) * 0.5f;
        const float szb = bh - bl;
        const float g = (c0 - pr[i]) / (pr[i + 3] / 10.0f);
        const float g2 = logf(szb / pr[i + 3]) * 5.0f;
        ls += fabsf(pl[i] - g) + fabsf(pl[i + 3] - g2);
      }
      d_lc += sgn * (double)ls;
    }
  }
  if (d_np) n_pos[b] += d_np;
  pconf[b] += d_cf;
  ploc[b] += d_lc;
}

// Cooperative block-wide radix select over BINS bins (descending cumulative).
template <int BINS>
__device__ void block_select(const unsigned* __restrict__ h, int remk,
                             unsigned* s_scan, int* s_out, unsigned* sel,
                             int* remk_o) {
  constexpr int BPT = BINS / 256;
  const int t = threadIdx.x;
  if (t == 0) { s_out[0] = BINS - 1; s_out[1] = 0; }
  unsigned mb[BPT];
  unsigned s = 0;
#pragma unroll
  for (int i = 0; i < BPT; ++i) { mb[i] = h[t * BPT + i]; s += mb[i]; }
  unsigned incl = s;
  s_scan[t] = incl;
  __syncthreads();
  for (int off = 1; off < 256; off <<= 1) {
    const unsigned add = (t >= off) ? s_scan[t - off] : 0u;
    __syncthreads();
    incl += add;
    s_scan[t] = incl;
    __syncthreads();
  }
  const unsigned total = s_scan[255];
  const unsigned R = total - incl;
  if (remk > 0 && R < (unsigned)remk && R + s >= (unsigned)remk) {
    unsigned acc = R;
    int sel_i = t * BPT, rk = 0;
    bool done = false;
#pragma unroll
    for (int i = BPT - 1; i >= 0; --i) {
      if (!done && acc + mb[i] >= (unsigned)remk) {
        sel_i = t * BPT + i;
        rk = remk - (int)acc;
        done = true;
      }
      if (!done) acc += mb[i];
    }
    s_out[0] = sel_i;
    s_out[1] = rk;
  }
  __syncthreads();
  *sel = (unsigned)s_out[0];
  *remk_o = s_out[1];
  __syncthreads();
}

__global__ __launch_bounds__(256) void mbl_hist1(
    const float* __restrict__ conf_neg, const int* __restrict__ n_pos,
    const unsigned* __restrict__ hist0, unsigned* __restrict__ hist1, int P) {
  const int b = blockIdx.y;
  const int tid = threadIdx.x;
  __shared__ unsigned s_scan[256];
  __shared__ int s_out[2];
  __shared__ unsigned s_hist[4096];
  int K = 3 * n_pos[b];
  if (K > P) K = P;
  unsigned sel0;
  int rem0;
  block_select<4096>(hist0 + (size_t)b * 4096, K, s_scan, s_out, &sel0, &rem0);
  for (int i = tid; i < 4096; i += 256) s_hist[i] = 0u;
  __syncthreads();
  const float* row = conf_neg + (size_t)b * P;
  const int n4 = P >> 2;
  const int per = (n4 + (int)gridDim.x - 1) / (int)gridDim.x;
  const int s4 = blockIdx.x * per, e4 = min(s4 + per, n4);
  for (int i = s4 + tid; i < e4; i += 256) {
    const float4 v = ((const float4*)row)[i];
    unsigned u;
    u = __float_as_uint(v.x); if ((u >> 20) == sel0) atomicAdd(&s_hist[(u >> 8) & 4095u], 1u);
    u = __float_as_uint(v.y); if ((u >> 20) == sel0) atomicAdd(&s_hist[(u >> 8) & 4095u], 1u);
    u = __float_as_uint(v.z); if ((u >> 20) == sel0) atomicAdd(&s_hist[(u >> 8) & 4095u], 1u);
    u = __float_as_uint(v.w); if ((u >> 20) == sel0) atomicAdd(&s_hist[(u >> 8) & 4095u], 1u);
  }
  if (blockIdx.x == 0)
    for (int p = (n4 << 2) + tid; p < P; p += 256) {
      const unsigned u = __float_as_uint(row[p]);
      if ((u >> 20) == sel0) atomicAdd(&s_hist[(u >> 8) & 4095u], 1u);
    }
  __syncthreads();
  for (int i = tid; i < 4096; i += 256)
    if (s_hist[i]) atomicAdd(&hist1[(size_t)b * 4096 + i], s_hist[i]);
}

// Sum above 24-bit threshold; boundary bin at midpoint; last block finalizes.
__global__ __launch_bounds__(256) void mbl_sum(
    const float* __restrict__ conf_neg, const int* __restrict__ n_pos,
    const unsigned* __restrict__ hist0, const unsigned* __restrict__ hist1,
    const double* __restrict__ pconf, const double* __restrict__ ploc,
    double* __restrict__ phard, unsigned* __restrict__ counter, int P, int B,
    float* __restrict__ out) {
  const int b = blockIdx.y;
  const int tid = threadIdx.x;
  __shared__ unsigned s_scan[256];
  __shared__ int s_out[2];
  int K = 3 * n_pos[b];
  if (K > P) K = P;
  unsigned sel0, sel1;
  int rem0, rem1;
  block_select<4096>(hist0 + (size_t)b * 4096, K, s_scan, s_out, &sel0, &rem0);
  block_select<4096>(hist1 + (size_t)b * 4096, rem0, s_scan, s_out, &sel1, &rem1);
  const unsigned pref24 = (sel0 << 12) | sel1;
  const unsigned tb = (pref24 << 8) | 0xFFu;
  const float* row = conf_neg + (size_t)b * P;
  const int n4 = P >> 2;
  const int per = (n4 + (int)gridDim.x - 1) / (int)gridDim.x;
  const int s4 = blockIdx.x * per, e4 = min(s4 + per, n4);
  double local = 0.0;
  for (int i = s4 + tid; i < e4; i += 256) {
    const float4 v = ((const float4*)row)[i];
    if (__float_as_uint(v.x) > tb) local += (double)v.x;
    if (__float_as_uint(v.y) > tb) local += (double)v.y;
    if (__float_as_uint(v.z) > tb) local += (double)v.z;
    if (__float_as_uint(v.w) > tb) local += (double)v.w;
  }
  if (blockIdx.x == 0) {
    for (int p = (n4 << 2) + tid; p < P; p += 256) {
      const float v = row[p];
      if (__float_as_uint(v) > tb) local += (double)v;
    }
    if (tid == 0 && rem1 > 0)
      local += (double)rem1 * (double)__uint_as_float((pref24 << 8) | 0x80u);
  }
  __shared__ double red[256];
  red[tid] = local;
  __syncthreads();
  for (int s = 128; s > 0; s >>= 1) {
    if (tid < s) red[tid] += red[tid + s];
    __syncthreads();
  }
  if (tid == 0) {
    if (red[0] != 0.0) atomicAdd(&phard[b], red[0]);
    __threadfence();
    const unsigned done = atomicAdd(counter, 1u);
    if (done == gridDim.x * gridDim.y - 1) {
      double tp = 0.0, cs = 0.0, ls = 0.0, hs = 0.0;
      for (int i = 0; i < B; ++i) {
        tp += (double)n_pos[i];
        cs += pconf[i];
        ls += ploc[i];
        hs += atomicAdd(&phard[i], 0.0);
      }
      out[0] = (float)((hs + cs) / tp);
      out[1] = (float)(ls / (tp * 6.0));
    }
  }
}

extern "C" void kernel_launch(void* const* d_in, const int* in_sizes, int n_in,
                              void* d_out, int out_size, void* d_ws, size_t ws_size,
                              hipStream_t stream) {
  const float* locs = (const float*)d_in[0];
  const float* scores = (const float*)d_in[1];
  const float* boxes = (const float*)d_in[2];
  const int* labels = (const int*)d_in[3];
  const float* priors = (const float*)d_in[4];

  const long long sz_locs = (long long)in_sizes[0];
  const long long sz_scores = (long long)in_sizes[1];
  const long long sz_priors = (long long)in_sizes[4];
  const int P = (int)(sz_priors / 6);
  const int B = (int)(sz_locs / sz_priors);
  const int n_obj = in_sizes[3] / B;
  const int C = (int)(sz_scores * 6 / sz_locs);

  char* ws = (char*)d_ws;
  size_t off = 0;
  double* pconf = (double*)(ws + off); off += (size_t)B * 8;
  double* ploc = (double*)(ws + off); off += (size_t)B * 8;
  double* phard = (double*)(ws + off); off += (size_t)B * 8;
  int* n_pos = (int*)(ws + off); off += ((size_t)B * 4 + 15) & ~(size_t)15;
  unsigned* counter = (unsigned*)(ws + off); off += 16;
  unsigned long long* prior_fo = (unsigned long long*)(ws + off);
  off += (size_t)B * 64 * 8;
  unsigned* hist0 = (unsigned*)(ws + off); off += (size_t)B * 4096 * 4;
  unsigned* hist1 = (unsigned*)(ws + off); off += (size_t)B * 4096 * 4;
  const size_t zero_bytes = off;
  float* conf_neg = (float*)(ws + off); off += ((size_t)B * P * 4 + 15) & ~(size_t)15;
  unsigned char* best_u8 = (unsigned char*)(ws + off);
  off += ((size_t)B * P + 15) & ~(size_t)15;
  (void)ws_size;

  hipMemsetAsync(d_ws, 0, zero_bytes, stream);

  const int tileF = LBF * 256;
  const int chunks = (P + tileF - 1) / tileF;
  const dim3 fgrid(LBF, B);
  if (C == 2)
    mbl_fused<2><<<fgrid, 256, 0, stream>>>(locs, scores, boxes, labels, priors,
                                            prior_fo, best_u8, conf_neg, hist0,
                                            n_pos, pconf, ploc, P, n_obj, chunks, C);
  else
    mbl_fused<0><<<fgrid, 256, 0, stream>>>(locs, scores, boxes, labels, priors,
                                            prior_fo, best_u8, conf_neg, hist0,
                                            n_pos, pconf, ploc, P, n_obj, chunks, C);

  mbl_fixup<<<B, 64, 0, stream>>>(locs, scores, boxes, labels, priors, prior_fo,
                                  best_u8, conf_neg, hist0, n_pos, pconf, ploc,
                                  P, n_obj, C);

  const dim3 lgrid(LB, B);
  mbl_hist1<<<lgrid, 256, 0, stream>>>(conf_neg, n_pos, hist0, hist1, P);
  mbl_sum<<<lgrid, 256, 0, stream>>>(conf_neg, n_pos, hist0, hist1, pconf, ploc,
                                     phard, counter, P, B, (float*)d_out);
}

// Round 11
// 92.412 us; speedup vs baseline: 1.3945x; 1.3945x over previous
//
#include <hip/hip_runtime.h>
#include <math.h>

#define MITEMS 2
#define TILE 512  // 256 * MITEMS
#define LB 32     // blocks per batch for loss/hist/sum kernels

// ---------------------------------------------------------------------------
// ws layout (memset region first):
//   double pconf[B], ploc[B], phard[B] ; int n_pos[B] ; u32 counter (+pad)
//   u64    prior_fo[B*64]   : packed (iou_bits<<32)|(0xFFFFFFFF-p), atomicMax
//   u32    hist0[B][4096], hist1[B][4096]
//   ---- end memset ----
//   float  conf_neg[B*P]
//   u8     best_u8[B*P]     : bit7 = (best iou >= 0.5), bits0-6 = best obj
// ---------------------------------------------------------------------------

__device__ __forceinline__ unsigned long long umax64(unsigned long long a,
                                                     unsigned long long b) {
  return a > b ? a : b;
}

// Match: r6 body (LDS s_box, exact per-prior bv/bo, exact per-object
// (iou,~p)), restructured pass-outer (8 objects live) + cheap transpose
// epilogue instead of 64-lane u64 butterflies.
template <int NOBJ, bool FULL>
__global__ __launch_bounds__(256) void mbl_match(
    const float* __restrict__ boxes, const float* __restrict__ priors,
    unsigned long long* __restrict__ prior_fo, unsigned char* __restrict__ best_u8,
    int P, int n_obj) {
  const int b = blockIdx.y;
  const int tid = threadIdx.x;
  __shared__ float4 s_box[NOBJ][2];  // {lo0,lo1,lo2,hi0},{hi1,hi2,vol,0}
  __shared__ unsigned s_iou[8][264];
  __shared__ unsigned s_pinv[8][264];
  for (int i = tid; i < NOBJ; i += 256) {
    float4 v0, v1;
    if (i < n_obj) {
      const float* bx = boxes + ((size_t)b * n_obj + i) * 6;
      const float l0 = bx[0], l1 = bx[1], l2 = bx[2];
      const float h0 = bx[3], h1 = bx[4], h2 = bx[5];
      v0 = make_float4(l0, l1, l2, h0);
      v1 = make_float4(h1, h2, ((h0 - l0) * (h1 - l1)) * (h2 - l2), 0.f);
    } else {  // dummy object: iou 0 vs everything
      v0 = make_float4(3e18f, 3e18f, 3e18f, 1e18f);
      v1 = make_float4(1e18f, 1e18f, 0.f, 0.f);
    }
    s_box[i][0] = v0;
    s_box[i][1] = v1;
  }
  __syncthreads();

  const int pbase = blockIdx.x * TILE;
  float lo0[MITEMS], lo1[MITEMS], lo2[MITEMS], hi0[MITEMS], hi1[MITEMS],
      hi2[MITEMS], vb[MITEMS];
  unsigned invp[MITEMS];
#pragma unroll
  for (int k = 0; k < MITEMS; ++k) {
    const int p = pbase + k * 256 + tid;
    if (FULL || p < P) {
      const float2 q0 = *(const float2*)(priors + (size_t)p * 6);
      const float2 q1 = *(const float2*)(priors + (size_t)p * 6 + 2);
      const float2 q2 = *(const float2*)(priors + (size_t)p * 6 + 4);
      lo0[k] = q0.x - q1.y * 0.5f; hi0[k] = q0.x + q1.y * 0.5f;
      lo1[k] = q0.y - q2.x * 0.5f; hi1[k] = q0.y + q2.x * 0.5f;
      lo2[k] = q1.x - q2.y * 0.5f; hi2[k] = q1.x + q2.y * 0.5f;
      vb[k] = (q1.y * q2.x) * q2.y;
      invp[k] = 0xFFFFFFFFu - (unsigned)p;
    } else {  // dummy prior: iou 0, never wins argmax (invp 0)
      lo0[k] = lo1[k] = lo2[k] = 3e18f;
      hi0[k] = hi1[k] = hi2[k] = 3e18f;
      vb[k] = 0.f;
      invp[k] = 0u;
    }
  }

  float bv[MITEMS];
  int bo[MITEMS];
#pragma unroll
  for (int k = 0; k < MITEMS; ++k) { bv[k] = -1.0f; bo[k] = 0; }

  for (int pass = 0; pass < NOBJ / 8; ++pass) {
    if (pass) __syncthreads();  // epilogue readers done before s_iou reuse
    float piou[8];
    unsigned pinv[8];
#pragma unroll
    for (int oo = 0; oo < 8; ++oo) { piou[oo] = 0.f; pinv[oo] = 0u; }

#pragma unroll
    for (int oo = 0; oo < 8; ++oo) {
      const int o = pass * 8 + oo;
      const float4 c0 = s_box[o][0];
      const float4 c1 = s_box[o][1];
#pragma unroll
      for (int k = 0; k < MITEMS; ++k) {
        const float d0 = fminf(c0.w, hi0[k]) - fmaxf(c0.x, lo0[k]);
        const float d1 = fminf(c1.x, hi1[k]) - fmaxf(c0.y, lo1[k]);
        const float d2 = fminf(c1.y, hi2[k]) - fmaxf(c0.z, lo2[k]);
        const float inter = (fmaxf(d0, 0.f) * fmaxf(d1, 0.f)) * fmaxf(d2, 0.f);
        const float un = (c1.z + vb[k]) - inter;
        const float iou = inter * __builtin_amdgcn_rcpf(un);
        if (iou > bv[k]) { bv[k] = iou; bo[k] = o; }  // first occurrence
        const bool win = iou > piou[oo];  // strict: keeps smaller k -> p
        piou[oo] = win ? iou : piou[oo];
        pinv[oo] = win ? invp[k] : pinv[oo];
      }
    }

    // cheap exact epilogue: padded transpose + 32-lane u64 butterfly
#pragma unroll
    for (int oo = 0; oo < 8; ++oo) {
      s_iou[oo][tid] = __float_as_uint(piou[oo]);
      s_pinv[oo][tid] = pinv[oo];
    }
    __syncthreads();
    const int obj8 = tid >> 5, j = tid & 31;
    unsigned long long m = 0ULL;
#pragma unroll
    for (int i = 0; i < 8; ++i) {
      const int col = j + 32 * i;
      m = umax64(m, ((unsigned long long)s_iou[obj8][col] << 32) |
                        s_pinv[obj8][col]);
    }
#pragma unroll
    for (int off = 1; off < 32; off <<= 1)
      m = umax64(m, __shfl_xor(m, off, 64));
    if (j == 0) {
      const int o = pass * 8 + obj8;
      if (o < n_obj) atomicMax(&prior_fo[(size_t)b * 64 + o], m);
    }
  }

#pragma unroll
  for (int k = 0; k < MITEMS; ++k) {
    const int p = pbase + k * 256 + tid;
    if (FULL || p < P)
      best_u8[(size_t)b * P + p] =
          (unsigned char)((unsigned)bo[k] | (bv[k] >= 0.5f ? 0x80u : 0u));
  }
}

// Loss: override scan + CE + loc L1 + conf_neg + fused 12-bit hist0.
template <int CC>
__global__ __launch_bounds__(256) void mbl_loss(
    const float* __restrict__ locs, const float* __restrict__ scores,
    const float* __restrict__ boxes, const int* __restrict__ labels,
    const float* __restrict__ priors, const unsigned long long* __restrict__ prior_fo,
    const unsigned char* __restrict__ best_u8, float* __restrict__ conf_neg,
    unsigned* __restrict__ hist0, int* __restrict__ n_pos,
    double* __restrict__ pconf, double* __restrict__ ploc, int P, int n_obj,
    int C) {
  const int b = blockIdx.y;
  const int tid = threadIdx.x;
  __shared__ float s_box[64][6];
  __shared__ int s_lab[64];
  __shared__ unsigned s_fo[64];
  __shared__ unsigned s_hist[4096];
  for (int i = tid; i < 4096; i += 256) s_hist[i] = 0u;
  for (int i = tid; i < n_obj * 6; i += 256)
    s_box[i / 6][i % 6] = boxes[(size_t)b * n_obj * 6 + i];
  for (int i = tid; i < n_obj; i += 256) {
    s_lab[i] = labels[(size_t)b * n_obj + i];
    s_fo[i] = 0xFFFFFFFFu - (unsigned)(prior_fo[(size_t)b * 64 + i] & 0xFFFFFFFFull);
  }
  __syncthreads();

  unsigned fo_r[16];
  const bool small_obj = (n_obj <= 16);
  if (small_obj) {
#pragma unroll
    for (int o = 0; o < 16; ++o) fo_r[o] = (o < n_obj) ? s_fo[o] : 0xFFFFFFFEu;
  }

  int np_l = 0;
  double cf_l = 0.0, lc_l = 0.0;

  if (CC == 2 && (P & 1) == 0) {
    const int P2 = P >> 1;
    const int chunk = (P2 + (int)gridDim.x - 1) / (int)gridDim.x;
    const int start = blockIdx.x * chunk;
    const int end = min(start + chunk, P2);
    for (int q = start + tid; q < end; q += 256) {
      const float4 sc = *(const float4*)(scores + ((size_t)b * P2 + q) * 4);
      const unsigned short bpp =
          *(const unsigned short*)(best_u8 + (size_t)b * P + 2 * q);
      float cn2[2];
#pragma unroll
      for (int e = 0; e < 2; ++e) {
        const int p = 2 * q + e;
        const unsigned bp = e ? (bpp >> 8) : (bpp & 0xFFu);
        int obj = bp & 0x7F;
        int posf = (int)(bp >> 7);
        if (small_obj) {
#pragma unroll
          for (int o = 0; o < 16; ++o)
            if (fo_r[o] == (unsigned)p) { obj = o; posf = 1; }  // last wins
        } else {
          for (int o = 0; o < n_obj; ++o)
            if (s_fo[o] == (unsigned)p) { obj = o; posf = 1; }
        }
        const int lab = posf ? s_lab[obj] : 0;
        const float sx = e ? sc.z : sc.x;
        const float sy = e ? sc.w : sc.y;
        const float mm = fmaxf(sx, sy);
        const float conf =
            (lab < 0) ? 0.f
                      : (mm + __logf(__expf(sx - mm) + __expf(sy - mm)) -
                         ((lab == 0) ? sx : sy));
        float cn = conf;
        if (lab > 0) {
          np_l++;
          cf_l += (double)conf;
          const float* pr = priors + (size_t)p * 6;
          const float* pl = locs + ((size_t)b * P + p) * 6;
          float ls = 0.f;
          for (int i = 0; i < 3; ++i) {
            const float c0 = (s_box[obj][i] + s_box[obj][i + 3]) * 0.5f;
            const float szb = s_box[obj][i + 3] - s_box[obj][i];
            const float g = (c0 - pr[i]) / (pr[i + 3] / 10.0f);
            const float g2 = logf(szb / pr[i + 3]) * 5.0f;
            ls += fabsf(pl[i] - g) + fabsf(pl[i + 3] - g2);
          }
          lc_l += (double)ls;
          cn = 0.f;
        }
        cn2[e] = cn;
        atomicAdd(&s_hist[__float_as_uint(cn) >> 20], 1u);
      }
      *(float2*)(conf_neg + (size_t)b * P + 2 * q) = make_float2(cn2[0], cn2[1]);
    }
  } else {
    const int chunk = (P + (int)gridDim.x - 1) / (int)gridDim.x;
    const int start = blockIdx.x * chunk;
    const int end = min(start + chunk, P);
    for (int p = start + tid; p < end; p += 256) {
      const unsigned char bp = best_u8[(size_t)b * P + p];
      int obj = bp & 0x7F;
      int posf = bp >> 7;
      for (int o = 0; o < n_obj; ++o)
        if (s_fo[o] == (unsigned)p) { obj = o; posf = 1; }
      const int lab = posf ? s_lab[obj] : 0;
      const float* sp = scores + ((size_t)b * P + p) * C;
      float m = sp[0];
      for (int c = 1; c < C; ++c) m = fmaxf(m, sp[c]);
      float se = 0.f;
      for (int c = 0; c < C; ++c) se += __expf(sp[c] - m);
      const float conf = (lab < 0) ? 0.f : (m + __logf(se) - sp[lab]);
      float cn = conf;
      if (lab > 0) {
        np_l++;
        cf_l += (double)conf;
        const float* pr = priors + (size_t)p * 6;
        const float* pl = locs + ((size_t)b * P + p) * 6;
        float ls = 0.f;
        for (int i = 0; i < 3; ++i) {
          const float c0 = (s_box[obj][i] + s_box[obj][i + 3]) * 0.5f;
          const float szb = s_box[obj][i + 3] - s_box[obj][i];
          const float g = (c0 - pr[i]) / (pr[i + 3] / 10.0f);
          const float g2 = logf(szb / pr[i + 3]) * 5.0f;
          ls += fabsf(pl[i] - g) + fabsf(pl[i + 3] - g2);
        }
        lc_l += (double)ls;
        cn = 0.f;
      }
      conf_neg[(size_t)b * P + p] = cn;
      atomicAdd(&s_hist[__float_as_uint(cn) >> 20], 1u);
    }
  }

  __shared__ int r_np[256];
  __shared__ double r_c[256];
  __shared__ double r_l[256];
  r_np[tid] = np_l;
  r_c[tid] = cf_l;
  r_l[tid] = lc_l;
  __syncthreads();
  for (int s = 128; s > 0; s >>= 1) {
    if (tid < s) {
      r_np[tid] += r_np[tid + s];
      r_c[tid] += r_c[tid + s];
      r_l[tid] += r_l[tid + s];
    }
    __syncthreads();
  }
  if (tid == 0 && r_np[0] > 0) {
    atomicAdd(&n_pos[b], r_np[0]);
    atomicAdd(&pconf[b], r_c[0]);
    atomicAdd(&ploc[b], r_l[0]);
  }
  for (int i = tid; i < 4096; i += 256)
    if (s_hist[i]) atomicAdd(&hist0[(size_t)b * 4096 + i], s_hist[i]);
}

// Cooperative block-wide radix select over BINS bins (descending cumulative).
template <int BINS>
__device__ void block_select(const unsigned* __restrict__ h, int remk,
                             unsigned* s_scan, int* s_out, unsigned* sel,
                             int* remk_o) {
  constexpr int BPT = BINS / 256;
  const int t = threadIdx.x;
  if (t == 0) { s_out[0] = BINS - 1; s_out[1] = 0; }
  unsigned mb[BPT];
  unsigned s = 0;
#pragma unroll
  for (int i = 0; i < BPT; ++i) { mb[i] = h[t * BPT + i]; s += mb[i]; }
  unsigned incl = s;
  s_scan[t] = incl;
  __syncthreads();
  for (int off = 1; off < 256; off <<= 1) {
    const unsigned add = (t >= off) ? s_scan[t - off] : 0u;
    __syncthreads();
    incl += add;
    s_scan[t] = incl;
    __syncthreads();
  }
  const unsigned total = s_scan[255];
  const unsigned R = total - incl;
  if (remk > 0 && R < (unsigned)remk && R + s >= (unsigned)remk) {
    unsigned acc = R;
    int sel_i = t * BPT, rk = 0;
    bool done = false;
#pragma unroll
    for (int i = BPT - 1; i >= 0; --i) {
      if (!done && acc + mb[i] >= (unsigned)remk) {
        sel_i = t * BPT + i;
        rk = remk - (int)acc;
        done = true;
      }
      if (!done) acc += mb[i];
    }
    s_out[0] = sel_i;
    s_out[1] = rk;
  }
  __syncthreads();
  *sel = (unsigned)s_out[0];
  *remk_o = s_out[1];
  __syncthreads();
}

__global__ __launch_bounds__(256) void mbl_hist1(
    const float* __restrict__ conf_neg, const int* __restrict__ n_pos,
    const unsigned* __restrict__ hist0, unsigned* __restrict__ hist1, int P) {
  const int b = blockIdx.y;
  const int tid = threadIdx.x;
  __shared__ unsigned s_scan[256];
  __shared__ int s_out[2];
  __shared__ unsigned s_hist[4096];
  int K = 3 * n_pos[b];
  if (K > P) K = P;
  unsigned sel0;
  int rem0;
  block_select<4096>(hist0 + (size_t)b * 4096, K, s_scan, s_out, &sel0, &rem0);
  for (int i = tid; i < 4096; i += 256) s_hist[i] = 0u;
  __syncthreads();
  const float* row = conf_neg + (size_t)b * P;
  const int n4 = P >> 2;
  const int per = (n4 + (int)gridDim.x - 1) / (int)gridDim.x;
  const int s4 = blockIdx.x * per, e4 = min(s4 + per, n4);
  for (int i = s4 + tid; i < e4; i += 256) {
    const float4 v = ((const float4*)row)[i];
    unsigned u;
    u = __float_as_uint(v.x); if ((u >> 20) == sel0) atomicAdd(&s_hist[(u >> 8) & 4095u], 1u);
    u = __float_as_uint(v.y); if ((u >> 20) == sel0) atomicAdd(&s_hist[(u >> 8) & 4095u], 1u);
    u = __float_as_uint(v.z); if ((u >> 20) == sel0) atomicAdd(&s_hist[(u >> 8) & 4095u], 1u);
    u = __float_as_uint(v.w); if ((u >> 20) == sel0) atomicAdd(&s_hist[(u >> 8) & 4095u], 1u);
  }
  if (blockIdx.x == 0)
    for (int p = (n4 << 2) + tid; p < P; p += 256) {
      const unsigned u = __float_as_uint(row[p]);
      if ((u >> 20) == sel0) atomicAdd(&s_hist[(u >> 8) & 4095u], 1u);
    }
  __syncthreads();
  for (int i = tid; i < 4096; i += 256)
    if (s_hist[i]) atomicAdd(&hist1[(size_t)b * 4096 + i], s_hist[i]);
}

// Sum above 24-bit threshold; boundary bin at midpoint; last block finalizes.
__global__ __launch_bounds__(256) void mbl_sum(
    const float* __restrict__ conf_neg, const int* __restrict__ n_pos,
    const unsigned* __restrict__ hist0, const unsigned* __restrict__ hist1,
    const double* __restrict__ pconf, const double* __restrict__ ploc,
    double* __restrict__ phard, unsigned* __restrict__ counter, int P, int B,
    float* __restrict__ out) {
  const int b = blockIdx.y;
  const int tid = threadIdx.x;
  __shared__ unsigned s_scan[256];
  __shared__ int s_out[2];
  int K = 3 * n_pos[b];
  if (K > P) K = P;
  unsigned sel0, sel1;
  int rem0, rem1;
  block_select<4096>(hist0 + (size_t)b * 4096, K, s_scan, s_out, &sel0, &rem0);
  block_select<4096>(hist1 + (size_t)b * 4096, rem0, s_scan, s_out, &sel1, &rem1);
  const unsigned pref24 = (sel0 << 12) | sel1;
  const unsigned tb = (pref24 << 8) | 0xFFu;
  const float* row = conf_neg + (size_t)b * P;
  const int n4 = P >> 2;
  const int per = (n4 + (int)gridDim.x - 1) / (int)gridDim.x;
  const int s4 = blockIdx.x * per, e4 = min(s4 + per, n4);
  double local = 0.0;
  for (int i = s4 + tid; i < e4; i += 256) {
    const float4 v = ((const float4*)row)[i];
    if (__float_as_uint(v.x) > tb) local += (double)v.x;
    if (__float_as_uint(v.y) > tb) local += (double)v.y;
    if (__float_as_uint(v.z) > tb) local += (double)v.z;
    if (__float_as_uint(v.w) > tb) local += (double)v.w;
  }
  if (blockIdx.x == 0) {
    for (int p = (n4 << 2) + tid; p < P; p += 256) {
      const float v = row[p];
      if (__float_as_uint(v) > tb) local += (double)v;
    }
    if (tid == 0 && rem1 > 0)
      local += (double)rem1 * (double)__uint_as_float((pref24 << 8) | 0x80u);
  }
  __shared__ double red[256];
  red[tid] = local;
  __syncthreads();
  for (int s = 128; s > 0; s >>= 1) {
    if (tid < s) red[tid] += red[tid + s];
    __syncthreads();
  }
  if (tid == 0) {
    if (red[0] != 0.0) atomicAdd(&phard[b], red[0]);
    __threadfence();
    const unsigned done = atomicAdd(counter, 1u);
    if (done == gridDim.x * gridDim.y - 1) {
      double tp = 0.0, cs = 0.0, ls = 0.0, hs = 0.0;
      for (int i = 0; i < B; ++i) {
        tp += (double)n_pos[i];
        cs += pconf[i];
        ls += ploc[i];
        hs += atomicAdd(&phard[i], 0.0);
      }
      out[0] = (float)((hs + cs) / tp);
      out[1] = (float)(ls / (tp * 6.0));
    }
  }
}

extern "C" void kernel_launch(void* const* d_in, const int* in_sizes, int n_in,
                              void* d_out, int out_size, void* d_ws, size_t ws_size,
                              hipStream_t stream) {
  const float* locs = (const float*)d_in[0];
  const float* scores = (const float*)d_in[1];
  const float* boxes = (const float*)d_in[2];
  const int* labels = (const int*)d_in[3];
  const float* priors = (const float*)d_in[4];

  const long long sz_locs = (long long)in_sizes[0];
  const long long sz_scores = (long long)in_sizes[1];
  const long long sz_priors = (long long)in_sizes[4];
  const int P = (int)(sz_priors / 6);
  const int B = (int)(sz_locs / sz_priors);
  const int n_obj = in_sizes[3] / B;
  const int C = (int)(sz_scores * 6 / sz_locs);

  char* ws = (char*)d_ws;
  size_t off = 0;
  double* pconf = (double*)(ws + off); off += (size_t)B * 8;
  double* ploc = (double*)(ws + off); off += (size_t)B * 8;
  double* phard = (double*)(ws + off); off += (size_t)B * 8;
  int* n_pos = (int*)(ws + off); off += ((size_t)B * 4 + 15) & ~(size_t)15;
  unsigned* counter = (unsigned*)(ws + off); off += 16;
  unsigned long long* prior_fo = (unsigned long long*)(ws + off);
  off += (size_t)B * 64 * 8;
  unsigned* hist0 = (unsigned*)(ws + off); off += (size_t)B * 4096 * 4;
  unsigned* hist1 = (unsigned*)(ws + off); off += (size_t)B * 4096 * 4;
  const size_t zero_bytes = off;
  float* conf_neg = (float*)(ws + off); off += ((size_t)B * P * 4 + 15) & ~(size_t)15;
  unsigned char* best_u8 = (unsigned char*)(ws + off);
  off += ((size_t)B * P + 15) & ~(size_t)15;
  (void)ws_size;

  hipMemsetAsync(d_ws, 0, zero_bytes, stream);

  const int nblk = (P + TILE - 1) / TILE;
  const dim3 mgrid(nblk, B);
  const bool full = (P % TILE) == 0;
  if (n_obj <= 16) {
    if (full) mbl_match<16, true><<<mgrid, 256, 0, stream>>>(boxes, priors, prior_fo, best_u8, P, n_obj);
    else      mbl_match<16, false><<<mgrid, 256, 0, stream>>>(boxes, priors, prior_fo, best_u8, P, n_obj);
  } else if (n_obj <= 32) {
    if (full) mbl_match<32, true><<<mgrid, 256, 0, stream>>>(boxes, priors, prior_fo, best_u8, P, n_obj);
    else      mbl_match<32, false><<<mgrid, 256, 0, stream>>>(boxes, priors, prior_fo, best_u8, P, n_obj);
  } else {
    if (full) mbl_match<64, true><<<mgrid, 256, 0, stream>>>(boxes, priors, prior_fo, best_u8, P, n_obj);
    else      mbl_match<64, false><<<mgrid, 256, 0, stream>>>(boxes, priors, prior_fo, best_u8, P, n_obj);
  }

  const dim3 lgrid(LB, B);
  if (C == 2)
    mbl_loss<2><<<lgrid, 256, 0, stream>>>(locs, scores, boxes, labels, priors,
                                           prior_fo, best_u8, conf_neg, hist0, n_pos,
                                           pconf, ploc, P, n_obj, C);
  else
    mbl_loss<0><<<lgrid, 256, 0, stream>>>(locs, scores, boxes, labels, priors,
                                           prior_fo, best_u8, conf_neg, hist0, n_pos,
                                           pconf, ploc, P, n_obj, C);

  mbl_hist1<<<lgrid, 256, 0, stream>>>(conf_neg, n_pos, hist0, hist1, P);
  mbl_sum<<<lgrid, 256, 0, stream>>>(conf_neg, n_pos, hist0, hist1, pconf, ploc,
                                     phard, counter, P, B, (float*)d_out);
}